// Round 6
// baseline (85.201 us; speedup 1.0000x reference)
//
#include <hip/hip_runtime.h>
#include <math.h>

// KANConv2D via bf16 MFMA 16x16x32, R12.
// R12: SINGLE kernel = R10 GEMM geometry + in-register B conversion with
// explicit 3-deep rotating prefetch (fixes R9's serial-latency failure:
// R9 had VGPR=40 so the compiler placed each fp32 B-load adjacent to its
// MFMA -> 72 serial L2 latencies). Here __launch_bounds__(512,2) allows
// 256 VGPR and the rotating slots force loads 3 steps ahead.
// Removes the cvt dispatch (~4us) + inter-kernel gap (~2us); d_ws unused
// (its poison fill is fixed harness overhead either way — R9 proved).
// Geometry (R10, verified): 196 blocks (4 b x 7x7 tiles of 8x8 px, M=64),
// 512 thr = 8 waves, wave = (nq 0..3: oc quarter) x (kh 0..1: K half),
// 4 A-frags x 36 k32-steps per wave, cross-wave spline+base K-reduction
// via LDS SoA, kh=0 waves do the epilogue.
// Base conv k-order = tap*32 + c (tap-major) -> A read from raw-x halo xh,
// no im2col scatter; base B = 40 strided fp32/lane preloaded before phase 1.
// Frag maps (validated R1/R6/R7/R10 + m89/m120):
//   A: m = lane&15 (+16f), k = (lane>>4)*8 + j
//   B: n = lane&15, k = (lane>>4)*8 + j
//   C/D: col = lane&15 = n, row = (lane>>4)*4 + reg (+16f).

typedef __attribute__((ext_vector_type(8))) short bf16x8;
typedef __attribute__((ext_vector_type(8))) float f32x8;
typedef __attribute__((ext_vector_type(4))) float f32x4;

#define MFMA16(a, b, c) __builtin_amdgcn_mfma_f32_16x16x32_bf16((a), (b), (c), 0, 0, 0)

__device__ __forceinline__ unsigned short f2bf(float f) {
    unsigned u = __builtin_bit_cast(unsigned, f);
    u = (u + 0x7fffu + ((u >> 16) & 1u)) >> 16;   // RNE
    return (unsigned short)u;
}

__device__ __forceinline__ bf16x8 cvt8(f32x8 w) {
    bf16x8 r;
    #pragma unroll
    for (int j = 0; j < 8; ++j) r[j] = (short)f2bf(w[j]);
    return r;
}

__device__ __forceinline__ void eval_bases(float v, float bs[8]) {
    #pragma unroll
    for (int i = 0; i < 8; ++i) bs[i] = 0.0f;
    // knots: t_g = (g-3)*0.4 - 1, support [-2.2, 2.2)
    float t = (v + 2.2f) * 2.5f;
    if (t >= 0.0f && t < 11.0f) {
        int j = (int)t;
        if (j > 10) j = 10;
        float knot = (float)(j - 3) * 0.4f - 1.0f;
        float u  = (v - knot) * 2.5f;
        float um = 1.0f - u;
        float u2 = u * u, u3 = u2 * u;
        const float s6 = 1.0f / 6.0f;
        float w0 = um * um * um * s6;
        float w1 = (3.0f * u3 - 6.0f * u2 + 4.0f) * s6;
        float w2 = (-3.0f * u3 + 3.0f * u2 + 3.0f * u + 1.0f) * s6;
        float w3 = u3 * s6;
        int i0 = j - 3;
        if (i0 >= 0)               bs[i0]     = w0;
        if (i0 + 1 >= 0 && i0 < 7) bs[i0 + 1] = w1;
        if (i0 + 2 >= 0 && i0 < 6) bs[i0 + 2] = w2;
        if (i0 + 3 <= 7)           bs[i0 + 3] = w3;
    }
}

__global__ __launch_bounds__(512, 2)
void kan_mfma_kernel(const float* __restrict__ x,
                     const float* __restrict__ wb,
                     const float* __restrict__ ws,
                     const float* __restrict__ sc,
                     float* __restrict__ out) {
    // sb: bases [c 0..31][hp 0..99][8]   = 25600 us (51200 B)
    // xh: raw x [hp 0..99][40: 32 c+pad] =  4000 us ( 8000 B)  total 59200 B
    __shared__ unsigned short smem[29600];
    unsigned short* sb = smem;
    unsigned short* xh = smem + 25600;

    const int tid = threadIdx.x;
    const int bx  = blockIdx.x;              // 0..195
    const int b   = bx / 49;
    const int r   = bx - b * 49;
    const int ty  = r / 7;
    const int tx  = r - ty * 7;
    const int h0  = ty * 8, w0 = tx * 8;

    const int lane = tid & 63;
    const int wv   = tid >> 6;        // 0..7
    const int nq   = wv & 3;          // oc quarter (16 oc)
    const int kh   = wv >> 1 & 0;     // placeholder (see below)
    const int khh  = wv >> 2;         // K half
    const int ml   = lane & 15;       // A row within frag / B,C col (oc)
    const int kg   = lane >> 4;       // k-group 0..3 within k32 step
    const int py0  = ml >> 3, px0 = ml & 7;   // frag-0 pixel (rows 0..15)
    (void)kh;

    // ---- phase 0a: issue x halo loads (longest dependency chain first) ----
    float vv[7];
    #pragma unroll
    for (int j = 0; j < 7; ++j) {
        int i = tid + j * 512;        // 0..3583
        float val = 0.0f;
        if (i < 3200) {
            int c  = i / 100;
            int hp = i - c * 100;
            int hy = hp / 10;
            int hx = hp - hy * 10;
            int hh = h0 + hy - 1, ww = w0 + hx - 1;
            if ((unsigned)hh < 56u && (unsigned)ww < 56u)
                val = x[((b * 32 + c) * 56 + hh) * 56 + ww];
        }
        vv[j] = val;
    }

    // ---- phase 0b: preload base-conv B (strided fp32, latency hides under ph1) ----
    // element: wb[(nq*16+ml)*288 + (kg*8+j)*9 + (s0+s)], k-order tap*32+c.
    const int s0  = khh ? 5 : 0;
    const int nST = khh ? 4 : 5;
    const float* wbsrc = wb + (nq * 16 + ml) * 288 + kg * 72 + s0;
    float wbp[5][8];
    #pragma unroll
    for (int s = 0; s < 5; ++s)
        if (s < nST) {
            #pragma unroll
            for (int j = 0; j < 8; ++j) wbp[s][j] = wbsrc[j * 9 + s];
        }

    // ---- phase 0c: prime spline-B rotating prefetch (slots S=0,1,2) ----
    // lane reads f32x8 at ws[(nq*16+ml)*2304 + (khh*36+S)*32 + kg*8].
    const float* wsrc = ws + (nq * 16 + ml) * 2304 + khh * 36 * 32 + kg * 8;
    f32x8 pw0 = *reinterpret_cast<const f32x8*>(wsrc);
    f32x8 pw1 = *reinterpret_cast<const f32x8*>(wsrc + 32);
    f32x8 pw2 = *reinterpret_cast<const f32x8*>(wsrc + 64);

    // ---- phase 1: eval bases, store sb + xh (1 store each, no scatter) ----
    #pragma unroll
    for (int j = 0; j < 7; ++j) {
        int i = tid + j * 512;
        if (i < 3200) {
            int c  = i / 100;
            int hp = i - c * 100;
            float bs[8];
            eval_bases(vv[j], bs);
            bf16x8 pk;
            #pragma unroll
            for (int j2 = 0; j2 < 8; ++j2) pk[j2] = (short)f2bf(bs[j2]);
            *reinterpret_cast<bf16x8*>(&sb[i * 8]) = pk;   // i = c*100+hp
            xh[hp * 40 + c] = f2bf(vv[j]);
        }
    }
    __syncthreads();

    // spline A offsets (ushort units): step S reads p = 4S + kg
    //   -> dc = (4u+kg)/9 within the g-quad, tap = (4u+kg)%9.
    // frag f = +2 tile rows = +f*160 ushorts.
    int aoff[9];
    #pragma unroll
    for (int u = 0; u < 9; ++u) {
        int tt  = 4 * u + kg;         // 0..35
        int dc  = tt / 9;
        int tap = tt - dc * 9;
        int th  = tap / 3;
        int tw  = tap - th * 3;
        aoff[u] = (dc * 100 + (py0 + th) * 10 + (px0 + tw)) * 8;
    }

    f32x4 aS[4] = {{0,0,0,0},{0,0,0,0},{0,0,0,0},{0,0,0,0}};
    f32x4 aB[4] = {{0,0,0,0},{0,0,0,0},{0,0,0,0},{0,0,0,0}};

    // ---- spline GEMM: 36 k32-steps, B cvt'd in-register, 3-deep prefetch ----
    const int kbase = khh * 12800;    // 4*khh channel-quads * 3200 ushorts
#define SPL_STEP(S, WREG) do {                                                   \
        bf16x8 bwv = cvt8(WREG);                                                 \
        if ((S) + 3 < 36)                                                        \
            WREG = *reinterpret_cast<const f32x8*>(wsrc + ((S) + 3) * 32);       \
        const int g_ = (S) / 9, u_ = (S) % 9;                                    \
        const int ab = kbase + g_ * 3200;                                        \
        bf16x8 a0 = *reinterpret_cast<const bf16x8*>(&sb[ab + aoff[u_]]);        \
        bf16x8 a1 = *reinterpret_cast<const bf16x8*>(&sb[ab + aoff[u_] + 160]);  \
        bf16x8 a2 = *reinterpret_cast<const bf16x8*>(&sb[ab + aoff[u_] + 320]);  \
        bf16x8 a3 = *reinterpret_cast<const bf16x8*>(&sb[ab + aoff[u_] + 480]);  \
        aS[0] = MFMA16(a0, bwv, aS[0]);                                          \
        aS[1] = MFMA16(a1, bwv, aS[1]);                                          \
        aS[2] = MFMA16(a2, bwv, aS[2]);                                          \
        aS[3] = MFMA16(a3, bwv, aS[3]);                                          \
    } while (0)

    #pragma unroll
    for (int Sb = 0; Sb < 36; Sb += 3) {
        SPL_STEP(Sb + 0, pw0);
        SPL_STEP(Sb + 1, pw1);
        SPL_STEP(Sb + 2, pw2);
    }
#undef SPL_STEP

    // ---- base GEMM (tap-major): khh=0 -> taps 0..4, khh=1 -> taps 5..8 ----
    #pragma unroll
    for (int s = 0; s < 5; ++s)
        if (s < nST) {
            const int tap = s0 + s;                    // wave-uniform
            const int th  = tap >= 6 ? 2 : (tap >= 3 ? 1 : 0);
            const int tw  = tap - 3 * th;
            bf16x8 bwv;
            #pragma unroll
            for (int j = 0; j < 8; ++j) bwv[j] = (short)f2bf(wbp[s][j]);
            const int xa = ((py0 + th) * 10 + (px0 + tw)) * 40 + kg * 8;
            #pragma unroll
            for (int f = 0; f < 4; ++f) {              // frag f = +2 rows = +800 us
                bf16x8 a = *reinterpret_cast<const bf16x8*>(&xh[xa + f * 800]);
                aB[f] = MFMA16(a, bwv, aB[f]);
            }
        }

    // ---- cross-wave K reduction via LDS (SoA: [32 words][260], conflict-free) ----
    __syncthreads();                               // all sb/xh reads done
    float* red = reinterpret_cast<float*>(smem);   // 32*260*4 = 33280 B
    const int idx = nq * 64 + lane;                // 0..255, same for the khh pair
    if (khh) {
        #pragma unroll
        for (int f = 0; f < 4; ++f) {
            #pragma unroll
            for (int w = 0; w < 4; ++w) red[(f * 4 + w) * 260 + idx] = aS[f][w];
        }
        #pragma unroll
        for (int f = 0; f < 4; ++f) {
            #pragma unroll
            for (int w = 0; w < 4; ++w) red[((16 + f * 4) + w) * 260 + idx] = aB[f][w];
        }
    }
    __syncthreads();
    if (!khh) {
        #pragma unroll
        for (int f = 0; f < 4; ++f) {
            #pragma unroll
            for (int w = 0; w < 4; ++w) aS[f][w] += red[(f * 4 + w) * 260 + idx];
        }
        #pragma unroll
        for (int f = 0; f < 4; ++f) {
            #pragma unroll
            for (int w = 0; w < 4; ++w) aB[f][w] += red[((16 + f * 4) + w) * 260 + idx];
        }

        // ---- epilogue: row m = f*16 + kg*4 + reg -> py = f*2+(kg>>1), px = (kg&1)*4+reg
        const int oc  = nq * 16 + ml;
        const float scv = sc[oc];
        #pragma unroll
        for (int f = 0; f < 4; ++f) {
            const int py  = f * 2 + (kg >> 1);
            const int pxb = (kg & 1) * 4;
            float* ob = out + ((b * 64 + oc) * 56 + h0 + py) * 56 + w0 + pxb;
            f32x4 res;
            #pragma unroll
            for (int reg = 0; reg < 4; ++reg) {
                float bv = aB[f][reg];
                float si = bv / (1.0f + __expf(-bv));
                res[reg] = si + scv * aS[f][reg];
            }
            *reinterpret_cast<f32x4*>(ob) = res;
        }
    }
}

extern "C" void kernel_launch(void* const* d_in, const int* in_sizes, int n_in,
                              void* d_out, int out_size, void* d_ws, size_t ws_size,
                              hipStream_t stream) {
    const float* x  = (const float*)d_in[0];   // (4,32,56,56)
    const float* wb = (const float*)d_in[1];   // (64,32,3,3)
    const float* ws = (const float*)d_in[2];   // (64,288,8)
    const float* sc = (const float*)d_in[3];   // (64,)
    float* out = (float*)d_out;                // (4,64,56,56)

    kan_mfma_kernel<<<196, 512, 0, stream>>>(x, wb, ws, sc, out);
}

// Round 7
// 73.610 us; speedup vs baseline: 1.1575x; 1.1575x over previous
//
#include <hip/hip_runtime.h>
#include <math.h>

// KANConv2D via bf16 MFMA 16x16x32, R13.
// R13 = R10 (best, 73.2us) + explicit double-buffered B-register prefetch.
// R9/R12 lesson: in-kernel fp32 B conversion always loses (2x bytes + compiler
// won't pipeline around cvt). Keep the cvt pre-pass; instead hide the bf16
// B-stream's L2/L3 latency (exposed at 1 block/CU = 2 waves/SIMD) with ILP:
// prefetch group g+1's nine bf16x8 B-frags into registers while group g's 36
// MFMAs run (g-loop fully unrolled -> all static indices), and preload the
// base-conv B frags before the spline loop (issued early, consumed late).
// - cvt kernel pre-swizzles fp32 weights -> bf16 MFMA B-frag streams in d_ws
//   (d_ws poison fill is fixed harness overhead regardless of use — R9).
// - Main: 196 blocks (4 b x 7x7 tiles of 8x8 px, M=64), 512 thr = 8 waves:
//   wave = (nq 0..3: oc quarter of 16) x (kh 0..1: K half), 4 A-frags x
//   36 k32-steps per wave, cross-wave K-reduction via LDS SoA, kh=0 waves
//   do the epilogue. Base conv k-order = tap*32 + c (tap-major) -> A read
//   from raw-x halo xh, no im2col scatter.
// Frag maps (validated R1/R6/R7/R10 + m89/m120):
//   A: m = lane&15 (+16f), k = (lane>>4)*8 + j
//   B: n = lane&15, k = (lane>>4)*8 + j
//   C/D: col = lane&15 = n, row = (lane>>4)*4 + reg (+16f).

typedef __attribute__((ext_vector_type(8))) short bf16x8;
typedef __attribute__((ext_vector_type(4))) float f32x4;

#define MFMA16(a, b, c) __builtin_amdgcn_mfma_f32_16x16x32_bf16((a), (b), (c), 0, 0, 0)

__device__ __forceinline__ unsigned short f2bf(float f) {
    unsigned u = __builtin_bit_cast(unsigned, f);
    u = (u + 0x7fffu + ((u >> 16) & 1u)) >> 16;   // RNE
    return (unsigned short)u;
}

__device__ __forceinline__ void eval_bases(float v, float bs[8]) {
    #pragma unroll
    for (int i = 0; i < 8; ++i) bs[i] = 0.0f;
    // knots: t_g = (g-3)*0.4 - 1, support [-2.2, 2.2)
    float t = (v + 2.2f) * 2.5f;
    if (t >= 0.0f && t < 11.0f) {
        int j = (int)t;
        if (j > 10) j = 10;
        float knot = (float)(j - 3) * 0.4f - 1.0f;
        float u  = (v - knot) * 2.5f;
        float um = 1.0f - u;
        float u2 = u * u, u3 = u2 * u;
        const float s6 = 1.0f / 6.0f;
        float w0 = um * um * um * s6;
        float w1 = (3.0f * u3 - 6.0f * u2 + 4.0f) * s6;
        float w2 = (-3.0f * u3 + 3.0f * u2 + 3.0f * u + 1.0f) * s6;
        float w3 = u3 * s6;
        int i0 = j - 3;
        if (i0 >= 0)               bs[i0]     = w0;
        if (i0 + 1 >= 0 && i0 < 7) bs[i0 + 1] = w1;
        if (i0 + 2 >= 0 && i0 < 6) bs[i0 + 2] = w2;
        if (i0 + 3 <= 7)           bs[i0 + 3] = w3;
    }
}

// ---- pre-kernel: fp32 weights -> bf16 B-frag streams ----
// wst (spline, k = p*8 + basis):
//   wst[((nq*72+S)*64+l)*8+j] = ws[(nq*16+(l&15))*2304 + S*32 + (l>>4)*8 + j]
// wbt (base, tap-major k = tap*32 + c):
//   wbt[((nq*9+s)*64+l)*8+j]  = wb[(nq*16+(l&15))*288 + ((l>>4)*8+j)*9 + s]
__global__ __launch_bounds__(256)
void cvt_swz_kernel(const float* __restrict__ ws, const float* __restrict__ wb,
                    unsigned short* __restrict__ wst, unsigned short* __restrict__ wbt) {
    int i = blockIdx.x * 256 + threadIdx.x;
    if (i < 147456) {
        int j = i & 7, l = (i >> 3) & 63, t = i >> 9;   // t 0..287
        int S = t % 72, nq = t / 72;
        int oc = nq * 16 + (l & 15);
        int k  = S * 32 + (l >> 4) * 8 + j;
        wst[i] = f2bf(ws[oc * 2304 + k]);
    } else {
        int i2 = i - 147456;
        if (i2 < 18432) {
            int j = i2 & 7, l = (i2 >> 3) & 63, t = i2 >> 9;  // t 0..35
            int s = t % 9, nq = t / 9;
            int oc = nq * 16 + (l & 15);
            int c  = (l >> 4) * 8 + j;
            wbt[i2] = f2bf(wb[oc * 288 + c * 9 + s]);
        }
    }
}

__global__ __launch_bounds__(512)
void kan_mfma_kernel(const float* __restrict__ x,
                     const float* __restrict__ sc,
                     const unsigned short* __restrict__ wst,
                     const unsigned short* __restrict__ wbt,
                     float* __restrict__ out) {
    // sb: bases [c 0..31][hp 0..99][8]   = 25600 us (51200 B)
    // xh: raw x [hp 0..99][40: 32 c+pad] =  4000 us ( 8000 B)  total 59200 B
    __shared__ unsigned short smem[29600];
    unsigned short* sb = smem;
    unsigned short* xh = smem + 25600;

    const int tid = threadIdx.x;
    const int bx  = blockIdx.x;              // 0..195
    const int b   = bx / 49;
    const int r   = bx - b * 49;
    const int ty  = r / 7;
    const int tx  = r - ty * 7;
    const int h0  = ty * 8, w0 = tx * 8;

    const int lane = tid & 63;
    const int wv   = tid >> 6;        // 0..7
    const int nq   = wv & 3;          // oc quarter (16 oc)
    const int kh   = wv >> 2;         // K half
    const int ml   = lane & 15;       // A row within frag / B,C col (oc)
    const int kg   = lane >> 4;       // k-group 0..3 within k32 step
    const int py0  = ml >> 3, px0 = ml & 7;   // frag-0 pixel (rows 0..15)

    // ---- phase 1: 3200 halo elems (10x10x32), batched loads, 1 store each ----
    float vv[7];
    #pragma unroll
    for (int j = 0; j < 7; ++j) {
        int i = tid + j * 512;        // 0..3583
        float val = 0.0f;
        if (i < 3200) {
            int c  = i / 100;
            int hp = i - c * 100;
            int hy = hp / 10;
            int hx = hp - hy * 10;
            int hh = h0 + hy - 1, ww = w0 + hx - 1;
            if ((unsigned)hh < 56u && (unsigned)ww < 56u)
                val = x[((b * 32 + c) * 56 + hh) * 56 + ww];
        }
        vv[j] = val;
    }
    #pragma unroll
    for (int j = 0; j < 7; ++j) {
        int i = tid + j * 512;
        if (i < 3200) {
            int c  = i / 100;
            int hp = i - c * 100;
            float bs[8];
            eval_bases(vv[j], bs);
            bf16x8 pk;
            #pragma unroll
            for (int j2 = 0; j2 < 8; ++j2) pk[j2] = (short)f2bf(bs[j2]);
            *reinterpret_cast<bf16x8*>(&sb[i * 8]) = pk;   // i = c*100+hp
            xh[hp * 40 + c] = f2bf(vv[j]);
        }
    }

    // ---- B prefetch (issued before the barrier: latency hides under ph1 tail) ----
    const unsigned short* bp = wst + ((nq * 72 + kh * 36) * 64 + lane) * 8;
    bf16x8 bwbuf[2][9];
    #pragma unroll
    for (int u = 0; u < 9; ++u)
        bwbuf[0][u] = *reinterpret_cast<const bf16x8*>(bp + u * 512);

    const int sbeg = kh ? 5 : 0;
    const int nST  = kh ? 4 : 5;
    bf16x8 bbv[5];
    {
        const unsigned short* bbp = wbt + (nq * 9 * 64 + lane) * 8;
        #pragma unroll
        for (int s = 0; s < 5; ++s)
            if (s < nST)
                bbv[s] = *reinterpret_cast<const bf16x8*>(bbp + (sbeg + s) * 512);
    }

    __syncthreads();

    // spline A offsets (ushort units): step S reads p = 4S + kg
    //   -> dc = (4u+kg)/9 within the g-quad, tap = (4u+kg)%9.
    // frag f = +2 tile rows = +f*160 ushorts.
    int aoff[9];
    #pragma unroll
    for (int u = 0; u < 9; ++u) {
        int tt  = 4 * u + kg;         // 0..35
        int dc  = tt / 9;
        int tap = tt - dc * 9;
        int th  = tap / 3;
        int tw  = tap - th * 3;
        aoff[u] = (dc * 100 + (py0 + th) * 10 + (px0 + tw)) * 8;
    }

    f32x4 aS[4] = {{0,0,0,0},{0,0,0,0},{0,0,0,0},{0,0,0,0}};
    f32x4 aB[4] = {{0,0,0,0},{0,0,0,0},{0,0,0,0},{0,0,0,0}};

    // ---- spline GEMM: 36 k32-steps, double-buffered 9-slot B prefetch ----
    // g fully unrolled -> bwbuf indices static (regs, no scratch).
    #pragma unroll
    for (int g = 0; g < 4; ++g) {
        const int cur = g & 1;
        if (g < 3) {
            #pragma unroll
            for (int u = 0; u < 9; ++u)
                bwbuf[cur ^ 1][u] =
                    *reinterpret_cast<const bf16x8*>(bp + ((g + 1) * 9 + u) * 512);
        }
        const int cbase = kh * 12800 + g * 3200;   // channel-quad base (us)
        #pragma unroll
        for (int u = 0; u < 9; ++u) {
            #pragma unroll
            for (int f = 0; f < 4; ++f) {
                bf16x8 a = *reinterpret_cast<const bf16x8*>(&sb[cbase + aoff[u] + f * 160]);
                aS[f] = MFMA16(a, bwbuf[cur][u], aS[f]);
            }
        }
    }

    // ---- base GEMM (tap-major): kh=0 -> taps 0..4, kh=1 -> taps 5..8 ----
    #pragma unroll
    for (int s = 0; s < 5; ++s)
        if (s < nST) {
            const int tap = sbeg + s;
            const int th  = tap >= 6 ? 2 : (tap >= 3 ? 1 : 0);
            const int tw  = tap - 3 * th;
            const int xa  = ((py0 + th) * 10 + (px0 + tw)) * 40 + kg * 8;
            #pragma unroll
            for (int f = 0; f < 4; ++f) {          // frag f = +2 rows = +800 us
                bf16x8 a = *reinterpret_cast<const bf16x8*>(&xh[xa + f * 800]);
                aB[f] = MFMA16(a, bbv[s], aB[f]);
            }
        }

    // ---- cross-wave K reduction via LDS (SoA: [32 words][260], conflict-free) ----
    __syncthreads();                               // all sb/xh reads done
    float* red = reinterpret_cast<float*>(smem);   // 32*260*4 = 33280 B
    const int idx = nq * 64 + lane;                // 0..255, same for the kh pair
    if (kh) {
        #pragma unroll
        for (int f = 0; f < 4; ++f) {
            #pragma unroll
            for (int w = 0; w < 4; ++w) red[(f * 4 + w) * 260 + idx] = aS[f][w];
        }
        #pragma unroll
        for (int f = 0; f < 4; ++f) {
            #pragma unroll
            for (int w = 0; w < 4; ++w) red[((16 + f * 4) + w) * 260 + idx] = aB[f][w];
        }
    }
    __syncthreads();
    if (!kh) {
        #pragma unroll
        for (int f = 0; f < 4; ++f) {
            #pragma unroll
            for (int w = 0; w < 4; ++w) aS[f][w] += red[(f * 4 + w) * 260 + idx];
        }
        #pragma unroll
        for (int f = 0; f < 4; ++f) {
            #pragma unroll
            for (int w = 0; w < 4; ++w) aB[f][w] += red[((16 + f * 4) + w) * 260 + idx];
        }

        // ---- epilogue: row m = f*16 + kg*4 + reg -> py = f*2+(kg>>1), px = (kg&1)*4+reg
        const int oc  = nq * 16 + ml;
        const float scv = sc[oc];
        #pragma unroll
        for (int f = 0; f < 4; ++f) {
            const int py  = f * 2 + (kg >> 1);
            const int pxb = (kg & 1) * 4;
            float* ob = out + ((b * 64 + oc) * 56 + h0 + py) * 56 + w0 + pxb;
            f32x4 res;
            #pragma unroll
            for (int reg = 0; reg < 4; ++reg) {
                float bv = aB[f][reg];
                float si = bv / (1.0f + __expf(-bv));
                res[reg] = si + scv * aS[f][reg];
            }
            *reinterpret_cast<f32x4*>(ob) = res;
        }
    }
}

extern "C" void kernel_launch(void* const* d_in, const int* in_sizes, int n_in,
                              void* d_out, int out_size, void* d_ws, size_t ws_size,
                              hipStream_t stream) {
    const float* x  = (const float*)d_in[0];   // (4,32,56,56)
    const float* wb = (const float*)d_in[1];   // (64,32,3,3)
    const float* ws = (const float*)d_in[2];   // (64,288,8)
    const float* sc = (const float*)d_in[3];   // (64,)
    float* out = (float*)d_out;                // (4,64,56,56)

    unsigned short* wst = (unsigned short*)d_ws;   // 147456 bf16
    unsigned short* wbt = wst + 147456;            // 18432 bf16

    cvt_swz_kernel<<<648, 256, 0, stream>>>(ws, wb, wst, wbt);
    kan_mfma_kernel<<<196, 512, 0, stream>>>(x, sc, wst, wbt, out);
}